// Round 4
// baseline (1321.875 us; speedup 1.0000x reference)
//
#include <hip/hip_runtime.h>
#include <math.h>

#define Bq 8
#define Hq 256
#define Wq 256
#define Cq 64
#define HID 8
#define PI_F 3.14159265358979323846f

typedef float f2 __attribute__((ext_vector_type(2)));

__device__ __forceinline__ f2 pkfma(f2 a, f2 b, f2 c) {
#if __has_builtin(__builtin_elementwise_fma)
    return __builtin_elementwise_fma(a, b, c);
#else
    f2 r; r.x = fmaf(a.x, b.x, c.x); r.y = fmaf(a.y, b.y, c.y); return r;
#endif
}
__device__ __forceinline__ f2 sp(float v) { f2 r; r.x = v; r.y = v; return r; }

// Sum v[hl&7] over the lane's OWN 32-lane half (two pixels per wave).
// Phase A folds value dim (strides 4,2,1); phase B sums groups (8,16).
__device__ __forceinline__ float fold8h(float v0, float v1, float v2, float v3,
                                        float v4, float v5, float v6, float v7,
                                        int hl) {
    const bool b4 = (hl & 4) != 0;
    float k0 = b4 ? v4 : v0, g0 = b4 ? v0 : v4;
    float k1 = b4 ? v5 : v1, g1 = b4 ? v1 : v5;
    float k2 = b4 ? v6 : v2, g2 = b4 ? v2 : v6;
    float k3 = b4 ? v7 : v3, g3 = b4 ? v3 : v7;
    k0 += __shfl_xor(g0, 4, 64);
    k1 += __shfl_xor(g1, 4, 64);
    k2 += __shfl_xor(g2, 4, 64);
    k3 += __shfl_xor(g3, 4, 64);
    const bool b2 = (hl & 2) != 0;
    float m0 = b2 ? k2 : k0, n0 = b2 ? k0 : k2;
    float m1 = b2 ? k3 : k1, n1 = b2 ? k1 : k3;
    m0 += __shfl_xor(n0, 2, 64);
    m1 += __shfl_xor(n1, 2, 64);
    const bool b1_ = (hl & 1) != 0;
    float q = b1_ ? m1 : m0, r = b1_ ? m0 : m1;
    q += __shfl_xor(r, 1, 64);
    q += __shfl_xor(q, 8, 64);    // stays within the 32-lane half
    q += __shfl_xor(q, 16, 64);
    return q;
}

// Packed bilinear sample: lane covers channels (2hl, 2hl+1) of its half's
// pixel. Clipped-integer-corner weights, faithful to the reference.
__device__ __forceinline__ void bilin2(const char* __restrict__ xb, unsigned laneoff,
                                       float cy, float cx, f2& acc) {
    float fy0 = floorf(cy), fx0 = floorf(cx);
    int y0 = (int)fy0, x0 = (int)fx0;
    int y0i = min(max(y0, 0), Hq - 1);
    int y1i = min(max(y0 + 1, 0), Hq - 1);
    int x0i = min(max(x0, 0), Wq - 1);
    int x1i = min(max(x0 + 1, 0), Wq - 1);
    float wy0 = (float)y1i - cy, wy1 = cy - (float)y0i;
    float wx0 = (float)x1i - cx, wx1 = cx - (float)x0i;
    unsigned r0 = ((unsigned)y0i << 16) + laneoff;
    unsigned r1 = ((unsigned)y1i << 16) + laneoff;
    unsigned c0 = (unsigned)x0i << 8, c1 = (unsigned)x1i << 8;
    f2 Ia = *(const f2*)(xb + (r0 + c0));
    f2 Ib = *(const f2*)(xb + (r1 + c0));
    f2 Ic = *(const f2*)(xb + (r0 + c1));
    f2 Id = *(const f2*)(xb + (r1 + c1));
    acc = pkfma(sp(wx0 * wy0), Ia, acc);
    acc = pkfma(sp(wx0 * wy1), Ib, acc);
    acc = pkfma(sp(wx1 * wy0), Ic, acc);
    acc = pkfma(sp(wx1 * wy1), Id, acc);
}

// Repack w3 [9][64][8] -> ws[tap][hl][j] = {w3[tap][2hl][j], w3[tap][2hl+1][j]}
// and wr [128][8] -> wrp/wrn pairs. 2816 f2 elements total.
__global__ void repack_kernel(const float* __restrict__ w3,
                              const float* __restrict__ wr,
                              f2* __restrict__ ws) {
    int t = blockIdx.x * 256 + threadIdx.x;
    if (t < 2304) {
        int tap = t >> 8, rem = t & 255, hl = rem >> 3, j = rem & 7;
        f2 v; v.x = w3[((tap << 6) + (hl << 1)) * 8 + j];
        v.y = w3[((tap << 6) + (hl << 1) + 1) * 8 + j];
        ws[t] = v;
    } else if (t < 2560) {
        int rem = t - 2304, hl = rem >> 3, j = rem & 7;
        f2 v; v.x = wr[(hl << 1) * 8 + j];
        v.y = wr[((hl << 1) + 1) * 8 + j];
        ws[t] = v;
    } else if (t < 2816) {
        int rem = t - 2560, hl = rem >> 3, j = rem & 7;
        f2 v; v.x = wr[(64 + (hl << 1)) * 8 + j];
        v.y = wr[(64 + (hl << 1) + 1) * 8 + j];
        ws[t] = v;
    }
}

__global__ __launch_bounds__(256) void oca_kernel(
    const float* __restrict__ x,
    const float* __restrict__ b3, const float* __restrict__ w1,
    const float* __restrict__ b1, const float* __restrict__ br,
    const float* __restrict__ we, const float* __restrict__ be,
    const f2* __restrict__ ws,
    float* __restrict__ out) {
    const int lane = threadIdx.x & 63;
    const int hl = lane & 31;               // lane within half-wave
    const int half = lane >> 5;             // 0: pixel 2w, 1: pixel 2w+1
    const int w = __builtin_amdgcn_readfirstlane(blockIdx.x * 4 + (threadIdx.x >> 6));
    // pixel pair p0=2w, p1=2w+1: same batch, same row always (2w even)
    const int b   = w >> 15;                // (2w)>>16
    const int yq  = (w >> 7) & 255;         // ((2w)>>8)&255
    const int xq0 = (2 * w) & 255;
    const int xql = xq0 + half;             // per-lane pixel x
    const char* xb = (const char*)(x + ((size_t)b << 22));
    const unsigned laneoff = (unsigned)hl << 3;   // channel-pair byte offset

    // ---- conv3x3 (packed channels), accumulate 8 hidden partials ----
    f2 a0 = sp(0.f), a1 = sp(0.f), a2 = sp(0.f), a3 = sp(0.f);
    f2 a4 = sp(0.f), a5 = sp(0.f), a6 = sp(0.f), a7 = sp(0.f);
    f2 xc2 = sp(0.f);                        // center pixel value (kept for output)
#pragma unroll
    for (int dy = -1; dy <= 1; ++dy) {
#pragma unroll
        for (int dx = -1; dx <= 1; ++dx) {
            int yy = yq + dy;
            int xx = xql + dx;
            int yyc = min(max(yy, 0), Hq - 1);
            int xxc = min(max(xx, 0), Wq - 1);
            bool valid = ((unsigned)yy < (unsigned)Hq) && ((unsigned)xx < (unsigned)Wq);
            f2 xv = *(const f2*)(xb + (((unsigned)yyc << 16) + ((unsigned)xxc << 8) + laneoff));
            xv = valid ? xv : sp(0.f);
            if (dy == 0 && dx == 0) xc2 = xv;
            const int tap = (dy + 1) * 3 + (dx + 1);
            const f2* wp = ws + (tap << 8) + (hl << 3);
            a0 = pkfma(xv, wp[0], a0);
            a1 = pkfma(xv, wp[1], a1);
            a2 = pkfma(xv, wp[2], a2);
            a3 = pkfma(xv, wp[3], a3);
            a4 = pkfma(xv, wp[4], a4);
            a5 = pkfma(xv, wp[5], a5);
            a6 = pkfma(xv, wp[6], a6);
            a7 = pkfma(xv, wp[7], a7);
        }
    }
    const int j = hl & 7;
    float hsum = fold8h(a0.x + a0.y, a1.x + a1.y, a2.x + a2.y, a3.x + a3.y,
                        a4.x + a4.y, a5.x + a5.y, a6.x + a6.y, a7.x + a7.y, hl);
    float h_l = fmaxf(hsum + b3[j], 0.f);

    // ---- theta = pi * sigmoid(w1 . h + b1), per half-wave ----
    float zp = h_l * w1[j];
    zp += __shfl_xor(zp, 1, 64);
    zp += __shfl_xor(zp, 2, 64);
    zp += __shfl_xor(zp, 4, 64);
    float z = zp + b1[0];
    float theta = PI_F * __builtin_amdgcn_rcpf(1.f + __expf(-z));
    float ct = __cosf(theta);
    float st = __sinf(theta);

    // ---- oriented pooling (tan & nor), packed channels ----
    const float fy = (float)yq, fx = (float)xql;
    f2 acc_t = sp(0.f), acc_n = sp(0.f);
#pragma unroll
    for (int t = -4; t <= 4; ++t) {
        float tf = (float)t;
        bilin2(xb, laneoff, fmaf(tf, st, fy), fmaf(tf, ct, fx), acc_t);
        bilin2(xb, laneoff, fmaf(tf, ct, fy), fmaf(-tf, st, fx), acc_n);
    }
    f2 tan2; tan2.x = acc_t.x * (1.f / 9.f); tan2.y = acc_t.y * (1.f / 9.f);
    f2 nor2; nor2.x = acc_n.x * (1.f / 9.f); nor2.y = acc_n.y * (1.f / 9.f);

    // ---- r = relu(wr . [tan;nor] + br) ----
    const f2* wrp = ws + 2304 + (hl << 3);
    const f2* wrn = ws + 2560 + (hl << 3);
    f2 p0 = pkfma(tan2, wrp[0], sp(0.f)); p0 = pkfma(nor2, wrn[0], p0);
    f2 p1 = pkfma(tan2, wrp[1], sp(0.f)); p1 = pkfma(nor2, wrn[1], p1);
    f2 p2 = pkfma(tan2, wrp[2], sp(0.f)); p2 = pkfma(nor2, wrn[2], p2);
    f2 p3 = pkfma(tan2, wrp[3], sp(0.f)); p3 = pkfma(nor2, wrn[3], p3);
    f2 p4 = pkfma(tan2, wrp[4], sp(0.f)); p4 = pkfma(nor2, wrn[4], p4);
    f2 p5 = pkfma(tan2, wrp[5], sp(0.f)); p5 = pkfma(nor2, wrn[5], p5);
    f2 p6 = pkfma(tan2, wrp[6], sp(0.f)); p6 = pkfma(nor2, wrn[6], p6);
    f2 p7 = pkfma(tan2, wrp[7], sp(0.f)); p7 = pkfma(nor2, wrn[7], p7);
    float rsum = fold8h(p0.x + p0.y, p1.x + p1.y, p2.x + p2.y, p3.x + p3.y,
                        p4.x + p4.y, p5.x + p5.y, p6.x + p6.y, p7.x + p7.y, hl);
    float r_l = fmaxf(rsum + br[j], 0.f);   // lane holds r[j], j = hl&7

    // broadcast within half: slot m holds r[j ^ m]
    float rb0 = r_l;
    float rb1 = __shfl_xor(rb0, 1, 64);
    float rb2 = __shfl_xor(rb0, 2, 64);
    float rb3 = __shfl_xor(rb1, 2, 64);
    float rb4 = __shfl_xor(rb0, 4, 64);
    float rb5 = __shfl_xor(rb1, 4, 64);
    float rb6 = __shfl_xor(rb2, 4, 64);
    float rb7 = __shfl_xor(rb3, 4, 64);

    // ---- w = sigmoid(we . r + be), packed channel pairs ----
    // row (j^m): byte = ((j^m)<<9) + (hl<<3); +256B for the zn (64..127) half
    const char* web = (const char*)we;
    unsigned voff = ((unsigned)j << 9) | laneoff;
    f2 zt2 = *(const f2*)((const char*)be + laneoff);
    f2 zn2 = *(const f2*)((const char*)be + 256 + laneoff);
#pragma unroll
    for (int m = 0; m < 8; ++m) {
        unsigned vm = voff ^ ((unsigned)m << 9);
        float rbm = (m == 0) ? rb0 : (m == 1) ? rb1 : (m == 2) ? rb2 : (m == 3) ? rb3
                  : (m == 4) ? rb4 : (m == 5) ? rb5 : (m == 6) ? rb6 : rb7;
        zt2 = pkfma(sp(rbm), *(const f2*)(web + vm), zt2);
        zn2 = pkfma(sp(rbm), *(const f2*)(web + vm + 256), zn2);
    }
    f2 wt2, wn2;
    wt2.x = __builtin_amdgcn_rcpf(1.f + __expf(-zt2.x));
    wt2.y = __builtin_amdgcn_rcpf(1.f + __expf(-zt2.y));
    wn2.x = __builtin_amdgcn_rcpf(1.f + __expf(-zn2.x));
    wn2.y = __builtin_amdgcn_rcpf(1.f + __expf(-zn2.y));

    f2 g; g.x = wt2.x + wn2.x; g.y = wt2.y + wn2.y;
    f2 o; o.x = g.x * xc2.x;   o.y = g.y * xc2.y;
    // out byte offset: pixel p=2w+half stride 256B, channel pair hl*8 -> lane*8
    *(f2*)((char*)out + (((size_t)w) << 9) + ((unsigned)lane << 3)) = o;
}

extern "C" void kernel_launch(void* const* d_in, const int* in_sizes, int n_in,
                              void* d_out, int out_size, void* d_ws, size_t ws_size,
                              hipStream_t stream) {
    const float* x  = (const float*)d_in[0];
    const float* w3 = (const float*)d_in[1];
    const float* b3 = (const float*)d_in[2];
    const float* w1 = (const float*)d_in[3];
    const float* b1 = (const float*)d_in[4];
    const float* wr = (const float*)d_in[5];
    const float* br = (const float*)d_in[6];
    const float* we = (const float*)d_in[7];
    const float* be = (const float*)d_in[8];
    float* out = (float*)d_out;
    f2* ws = (f2*)d_ws;

    repack_kernel<<<11, 256, 0, stream>>>(w3, wr, ws);

    const int total_waves = Bq * Hq * Wq / 2;   // one wave per pixel PAIR
    dim3 grid(total_waves / 4), block(256);     // 4 waves per block
    oca_kernel<<<grid, block, 0, stream>>>(x, b3, w1, b1, br, we, be, ws, out);
}